// Round 5
// baseline (505.201 us; speedup 1.0000x reference)
//
#include <hip/hip_runtime.h>
#include <hip/hip_bf16.h>
#include <stdint.h>

#define T_TOK 4096
#define D_DIM 1024
#define E_EXP 8
#define I_DIM 938
#define TWO_I 1876
#define NP2 2048       // interleaved gate/up rows: row 2c = gate col c, 2c+1 = up col c
#define IP 1024        // padded I

typedef __attribute__((ext_vector_type(8))) short bf16x8;
typedef __attribute__((ext_vector_type(4))) float f32x4;
typedef __attribute__((ext_vector_type(8))) unsigned short u16x8;
typedef __attribute__((ext_vector_type(4))) unsigned short u16x4;

static __device__ __forceinline__ unsigned short f2bf(float f) {
  union { float f; uint32_t u; } v; v.f = f;
  uint32_t r = v.u + 0x7fffu + ((v.u >> 16) & 1u);
  return (unsigned short)(r >> 16);
}
static __device__ __forceinline__ void gload16(const void* g, void* l) {
  __builtin_amdgcn_global_load_lds((__attribute__((address_space(1))) void*)g,
                                   (__attribute__((address_space(3))) void*)l, 16, 0, 0);
}

// ---------------- x fp32 -> bf16 ----------------
__global__ __launch_bounds__(256) void cvt_x_kernel(const float* __restrict__ x,
                                                    unsigned short* __restrict__ xb) {
  int i = blockIdx.x * 256 + threadIdx.x;
  float4 v = reinterpret_cast<const float4*>(x)[i];
  u16x4 o;
  o[0] = f2bf(v.x); o[1] = f2bf(v.y); o[2] = f2bf(v.z); o[3] = f2bf(v.w);
  reinterpret_cast<u16x4*>(xb)[i] = o;
}

// ---------------- router: top-2 (idx, weight) per token ----------------
__global__ __launch_bounds__(256) void router_kernel(const float* __restrict__ x,
                                                     const float* __restrict__ gw,
                                                     int* __restrict__ ti,
                                                     float* __restrict__ tw) {
  int t = blockIdx.x * 4 + (threadIdx.x >> 6);
  int lane = threadIdx.x & 63;
  const float* xp = x + (size_t)t * D_DIM;
  float xv[16];
  #pragma unroll
  for (int i = 0; i < 16; ++i) xv[i] = xp[lane + i * 64];
  float logit[E_EXP];
  #pragma unroll
  for (int e = 0; e < E_EXP; ++e) {
    const float* wp = gw + (size_t)e * D_DIM;
    float s = 0.f;
    #pragma unroll
    for (int i = 0; i < 16; ++i) s += xv[i] * wp[lane + i * 64];
    #pragma unroll
    for (int o = 32; o; o >>= 1) s += __shfl_xor(s, o);
    logit[e] = s;
  }
  float mx = logit[0];
  #pragma unroll
  for (int e = 1; e < E_EXP; ++e) mx = fmaxf(mx, logit[e]);
  float p[E_EXP], sum = 0.f;
  #pragma unroll
  for (int e = 0; e < E_EXP; ++e) { p[e] = __expf(logit[e] - mx); sum += p[e]; }
  int i1 = 0; float p1 = p[0];
  #pragma unroll
  for (int e = 1; e < E_EXP; ++e) if (p[e] > p1) { p1 = p[e]; i1 = e; }
  int i2 = -1; float p2 = -1.f;
  #pragma unroll
  for (int e = 0; e < E_EXP; ++e) if (e != i1 && p[e] > p2) { p2 = p[e]; i2 = e; }
  float P1 = p1 / sum, P2 = p2 / sum;
  float denom = P1 + P2 + 1e-8f;
  if (lane == 0) {
    ti[2 * t] = i1; ti[2 * t + 1] = i2;
    tw[2 * t] = P1 / denom; tw[2 * t + 1] = P2 / denom;
  }
}

__global__ void zero_cnt_kernel(int* cnt) { if (threadIdx.x < E_EXP) cnt[threadIdx.x] = 0; }

__global__ __launch_bounds__(256) void assign_kernel(const int* __restrict__ ti,
                                                     const float* __restrict__ tw,
                                                     int* __restrict__ cnt,
                                                     int* __restrict__ list,
                                                     float* __restrict__ wl, int cap) {
  int t = blockIdx.x * 256 + threadIdx.x;
  #pragma unroll
  for (int j = 0; j < 2; ++j) {
    int e = ti[2 * t + j];
    float w = tw[2 * t + j];
    int slot = atomicAdd(&cnt[e], 1);
    if (slot < cap) { list[e * cap + slot] = t; wl[e * cap + slot] = w; }
  }
}

// ---- transpose gate_up: w[k][col] -> wT[n][k] bf16, gate/up INTERLEAVED ----
// output row 2c = gate col c; row 2c+1 = up col c (zero-pad past I_DIM)
__global__ __launch_bounds__(256) void transpose_gu_kernel(
    const float* __restrict__ sgu, const float* __restrict__ egu,
    unsigned short* __restrict__ wT) {
  int e = blockIdx.z;
  const float* w = (e == 0) ? sgu : egu + (size_t)(e - 1) * D_DIM * TWO_I;
  unsigned short* o = wT + (size_t)e * NP2 * D_DIM;
  int k0 = blockIdx.x * 64, n0 = blockIdx.y * 32;
  __shared__ unsigned short lds[32][72];
  int tid = threadIdx.x;
  int nn = tid & 31, kr = tid >> 5;
  int n = n0 + nn;
  int hc = n >> 1;
  int src = (hc < I_DIM) ? ((n & 1) ? (I_DIM + hc) : hc) : -1;
  #pragma unroll
  for (int i = 0; i < 8; ++i) {
    int k = k0 + kr + i * 8;
    float f = (src >= 0) ? w[(size_t)k * TWO_I + src] : 0.f;
    lds[nn][kr + i * 8] = f2bf(f);
  }
  __syncthreads();
  int nr = tid >> 3, kc = (tid & 7) * 8;
  u16x8 v;
  #pragma unroll
  for (int j = 0; j < 8; ++j) v[j] = lds[nr][kc + j];
  *reinterpret_cast<u16x8*>(&o[(size_t)(n0 + nr) * D_DIM + k0 + kc]) = v;
}

// ---- transpose down: wd[k][n] -> wT[n][k] bf16, k padded to 1024 ----
__global__ __launch_bounds__(256) void transpose_d_kernel(
    const float* __restrict__ sdn, const float* __restrict__ edn,
    unsigned short* __restrict__ wT) {
  int e = blockIdx.z;
  const float* w = (e == 0) ? sdn : edn + (size_t)(e - 1) * I_DIM * D_DIM;
  unsigned short* o = wT + (size_t)e * D_DIM * IP;
  int k0 = blockIdx.x * 64, n0 = blockIdx.y * 32;
  __shared__ unsigned short lds[32][72];
  int tid = threadIdx.x;
  int nn = tid & 31, kr = tid >> 5;
  #pragma unroll
  for (int i = 0; i < 8; ++i) {
    int k = k0 + kr + i * 8;
    float f = (k < I_DIM) ? w[(size_t)k * D_DIM + n0 + nn] : 0.f;
    lds[nn][kr + i * 8] = f2bf(f);
  }
  __syncthreads();
  int nr = tid >> 3, kc = (tid & 7) * 8;
  u16x8 v;
  #pragma unroll
  for (int j = 0; j < 8; ++j) v[j] = lds[nr][kc + j];
  *reinterpret_cast<u16x8*>(&o[(size_t)(n0 + nr) * IP + k0 + kc]) = v;
}

// ------- GEMM1+SwiGLU: 256x256 tile, BK=64, 512 thr (8 waves 2Mx4N) -------
// grid 1D 640 = 128 shared (16mb x 8nb) + 8 experts x 64 (8mb x 8nb), swizzled
__global__ __launch_bounds__(512) void gemm1_kernel(
    const unsigned short* __restrict__ xb,
    const unsigned short* __restrict__ wTgu,
    unsigned short* __restrict__ h_sh,
    unsigned short* __restrict__ h_g,
    const int* __restrict__ list, const int* __restrict__ cnt, int cap) {
  const int orig = blockIdx.x;
  const int wg = (orig & 7) * (gridDim.x >> 3) + (orig >> 3);   // bijective, 640%8==0
  int e, mb, nb;
  if (wg < 128) { e = 0; mb = wg >> 3; nb = wg & 7; }
  else { int r = wg - 128; e = 1 + (r >> 6); int rem = r & 63; mb = rem >> 3; nb = rem & 7; }
  const int m0 = mb * 256, n0 = nb * 256;
  int count = T_TOK;
  unsigned short* h = h_sh;
  if (e > 0) {
    count = min(cnt[e - 1], cap);
    if (m0 >= count) return;
    h = h_g + (size_t)(e - 1) * cap * IP;
  }
  const unsigned short* w = wTgu + (size_t)e * NP2 * D_DIM;

  __shared__ __align__(16) unsigned short a_lds[256 * 64];
  __shared__ __align__(16) unsigned short b_lds[256 * 64];
  const int tid = threadIdx.x;
  const int wave = tid >> 6, lane = tid & 63;
  const int mw = (wave >> 2) * 128, nw = (wave & 3) * 64;
  const int fr = lane & 15, fq = lane >> 4;
  const int srow = tid >> 3;            // staging row within 64-row chunk
  const int sk = (tid & 7) * 8;         // staging k-offset (shorts)

  size_t arow[4], brow[4];
  #pragma unroll
  for (int c = 0; c < 4; ++c) {
    int rr = m0 + 64 * c + srow;
    if (e > 0) rr = list[(e - 1) * cap + min(rr, count - 1)];
    arow[c] = (size_t)rr * D_DIM;
    brow[c] = (size_t)(n0 + 64 * c + srow) * D_DIM;
  }

  f32x4 acc[8][4];
  #pragma unroll
  for (int m = 0; m < 8; ++m)
    #pragma unroll
    for (int n = 0; n < 4; ++n) acc[m][n] = (f32x4)0.f;

  for (int k0 = 0; k0 < D_DIM; k0 += 64) {
    __syncthreads();
    #pragma unroll
    for (int c = 0; c < 4; ++c) {
      gload16(xb + arow[c] + k0 + sk, &a_lds[(64 * c + srow) * 64 + sk]);
      gload16(w + brow[c] + k0 + sk, &b_lds[(64 * c + srow) * 64 + sk]);
    }
    __syncthreads();
    #pragma unroll
    for (int kk = 0; kk < 2; ++kk) {
      bf16x8 av[8], bv[4];
      #pragma unroll
      for (int m = 0; m < 8; ++m)
        av[m] = *reinterpret_cast<const bf16x8*>(&a_lds[(mw + m * 16 + fr) * 64 + kk * 32 + fq * 8]);
      #pragma unroll
      for (int n = 0; n < 4; ++n)
        bv[n] = *reinterpret_cast<const bf16x8*>(&b_lds[(nw + n * 16 + fr) * 64 + kk * 32 + fq * 8]);
      #pragma unroll
      for (int m = 0; m < 8; ++m)
        #pragma unroll
        for (int n = 0; n < 4; ++n)
          acc[m][n] = __builtin_amdgcn_mfma_f32_16x16x32_bf16(av[m], bv[n], acc[m][n], 0, 0, 0);
    }
  }
  // epilogue: even B-row = gate, odd = up (same h-col); pair via shfl_xor(1)
  const bool isGate = !(fr & 1);
  const int hcb = (n0 + nw) >> 1;
  #pragma unroll
  for (int m = 0; m < 8; ++m)
    #pragma unroll
    for (int n = 0; n < 4; ++n)
      #pragma unroll
      for (int q = 0; q < 4; ++q) {
        float v = acc[m][n][q];
        float pt = __shfl_xor(v, 1);
        if (isGate) {
          float hv = (v / (1.f + __expf(-v))) * pt;
          int trow = m0 + mw + m * 16 + fq * 4 + q;
          h[(size_t)trow * IP + hcb + n * 8 + (fr >> 1)] = f2bf(hv);
        }
      }
}

// ------- GEMM2 fused: out(zeroed) += wgt * (h @ Wd), 256x256, atomic epi -------
// grid 1D 320 = 64 shared (16mb x 4nb) + 8 experts x 32 (8mb x 4nb), swizzled
__global__ __launch_bounds__(512) void gemm2_kernel(
    const unsigned short* __restrict__ h_sh,
    const unsigned short* __restrict__ h_g,
    const unsigned short* __restrict__ wTd,
    float* __restrict__ out,
    const int* __restrict__ list, const float* __restrict__ wl,
    const int* __restrict__ cnt, int cap) {
  const int orig = blockIdx.x;
  const int wg = (orig & 7) * (gridDim.x >> 3) + (orig >> 3);   // 320%8==0
  int e, mb, nb;
  if (wg < 64) { e = -1; mb = wg >> 2; nb = wg & 3; }
  else { int r = wg - 64; e = r >> 5; int rem = r & 31; mb = rem >> 2; nb = rem & 3; }
  const int m0 = mb * 256, n0 = nb * 256;
  int count = T_TOK;
  const unsigned short* A = h_sh;
  if (e >= 0) {
    count = min(cnt[e], cap);
    if (m0 >= count) return;
    A = h_g + (size_t)e * cap * IP;
  }
  const unsigned short* B = wTd + (size_t)(e + 1) * D_DIM * IP;

  __shared__ __align__(16) unsigned short a_lds[256 * 64];
  __shared__ __align__(16) unsigned short b_lds[256 * 64];
  const int tid = threadIdx.x;
  const int wave = tid >> 6, lane = tid & 63;
  const int mw = (wave >> 2) * 128, nw = (wave & 3) * 64;
  const int fr = lane & 15, fq = lane >> 4;
  const int srow = tid >> 3;
  const int sk = (tid & 7) * 8;

  f32x4 acc[8][4];
  #pragma unroll
  for (int m = 0; m < 8; ++m)
    #pragma unroll
    for (int n = 0; n < 4; ++n) acc[m][n] = (f32x4)0.f;

  for (int k0 = 0; k0 < IP; k0 += 64) {
    __syncthreads();
    #pragma unroll
    for (int c = 0; c < 4; ++c) {
      gload16(A + (size_t)(m0 + 64 * c + srow) * IP + k0 + sk,
              &a_lds[(64 * c + srow) * 64 + sk]);
      gload16(B + (size_t)(n0 + 64 * c + srow) * IP + k0 + sk,
              &b_lds[(64 * c + srow) * 64 + sk]);
    }
    __syncthreads();
    #pragma unroll
    for (int kk = 0; kk < 2; ++kk) {
      bf16x8 av[8], bv[4];
      #pragma unroll
      for (int m = 0; m < 8; ++m)
        av[m] = *reinterpret_cast<const bf16x8*>(&a_lds[(mw + m * 16 + fr) * 64 + kk * 32 + fq * 8]);
      #pragma unroll
      for (int n = 0; n < 4; ++n)
        bv[n] = *reinterpret_cast<const bf16x8*>(&b_lds[(nw + n * 16 + fr) * 64 + kk * 32 + fq * 8]);
      #pragma unroll
      for (int m = 0; m < 8; ++m)
        #pragma unroll
        for (int n = 0; n < 4; ++n)
          acc[m][n] = __builtin_amdgcn_mfma_f32_16x16x32_bf16(av[m], bv[n], acc[m][n], 0, 0, 0);
    }
  }
  #pragma unroll
  for (int m = 0; m < 8; ++m)
    #pragma unroll
    for (int q = 0; q < 4; ++q) {
      int slot = m0 + mw + m * 16 + fq * 4 + q;
      if (slot < count) {
        int t = slot; float wgt = 1.f;
        if (e >= 0) { t = list[e * cap + slot]; wgt = wl[e * cap + slot]; }
        #pragma unroll
        for (int n = 0; n < 4; ++n)
          atomicAdd(&out[(size_t)t * D_DIM + n0 + nw + n * 16 + fr], wgt * acc[m][n][q]);
      }
    }
}

extern "C" void kernel_launch(void* const* d_in, const int* in_sizes, int n_in,
                              void* d_out, int out_size, void* d_ws, size_t ws_size,
                              hipStream_t stream) {
  const float* x   = (const float*)d_in[0];
  const float* gw  = (const float*)d_in[1];
  const float* sgu = (const float*)d_in[2];
  const float* sdn = (const float*)d_in[3];
  const float* egu = (const float*)d_in[4];
  const float* edn = (const float*)d_in[5];
  float* out = (float*)d_out;

  char* p = (char*)d_ws;
  unsigned short* xb   = (unsigned short*)p; p += (size_t)T_TOK * D_DIM * 2;
  unsigned short* wTgu = (unsigned short*)p; p += (size_t)9 * NP2 * D_DIM * 2;
  unsigned short* wTd  = (unsigned short*)p; p += (size_t)9 * D_DIM * IP * 2;
  unsigned short* h_sh = (unsigned short*)p; p += (size_t)T_TOK * IP * 2;

  size_t fixed_tail = (size_t)T_TOK * 2 * (4 + 4) + 64 + 256;
  size_t used = (size_t)(p - (char*)d_ws) + fixed_tail;
  size_t per_cap = (size_t)E_EXP * (IP * 2 + 4 + 4);
  long avail = (long)ws_size - (long)used;
  int cap = (int)(avail > 0 ? avail / (long)per_cap : 0);
  cap &= ~255;                 // 256-tile alignment
  if (cap > 2048) cap = 2048;
  if (cap < 1536) cap = 1536;

  unsigned short* h_g = (unsigned short*)p; p += (size_t)E_EXP * cap * IP * 2;
  int*   ti   = (int*)p;   p += (size_t)T_TOK * 2 * 4;
  float* tw   = (float*)p; p += (size_t)T_TOK * 2 * 4;
  int*   list = (int*)p;   p += (size_t)E_EXP * cap * 4;
  float* wl   = (float*)p; p += (size_t)E_EXP * cap * 4;
  int*   cnt  = (int*)p;

  cvt_x_kernel<<<(T_TOK * D_DIM) / (4 * 256), 256, 0, stream>>>(x, xb);
  router_kernel<<<T_TOK / 4, 256, 0, stream>>>(x, gw, ti, tw);
  zero_cnt_kernel<<<1, 64, 0, stream>>>(cnt);
  assign_kernel<<<T_TOK / 256, 256, 0, stream>>>(ti, tw, cnt, list, wl, cap);
  transpose_gu_kernel<<<dim3(D_DIM / 64, NP2 / 32, 9), 256, 0, stream>>>(sgu, egu, wTgu);
  transpose_d_kernel<<<dim3(IP / 64, D_DIM / 32, 9), 256, 0, stream>>>(sdn, edn, wTd);
  hipMemsetAsync(d_out, 0, (size_t)out_size * 4, stream);

  gemm1_kernel<<<128 + E_EXP * 64, 512, 0, stream>>>(xb, wTgu, h_sh, h_g, list, cnt, cap);
  gemm2_kernel<<<64 + E_EXP * 32, 512, 0, stream>>>(h_sh, h_g, wTd, out, list, wl, cnt, cap);
}

// Round 6
// 461.489 us; speedup vs baseline: 1.0947x; 1.0947x over previous
//
#include <hip/hip_runtime.h>
#include <hip/hip_bf16.h>
#include <stdint.h>

#define T_TOK 4096
#define D_DIM 1024
#define E_EXP 8
#define I_DIM 938
#define TWO_I 1876
#define NP2 2048       // interleaved gate/up rows: row 2c = gate col c, 2c+1 = up col c
#define IP 1024        // padded I

typedef __attribute__((ext_vector_type(8))) short bf16x8;
typedef __attribute__((ext_vector_type(4))) float f32x4;
typedef __attribute__((ext_vector_type(8))) unsigned short u16x8;
typedef __attribute__((ext_vector_type(4))) unsigned short u16x4;

static __device__ __forceinline__ unsigned short f2bf(float f) {
  union { float f; uint32_t u; } v; v.f = f;
  uint32_t r = v.u + 0x7fffu + ((v.u >> 16) & 1u);
  return (unsigned short)(r >> 16);
}
static __device__ __forceinline__ void gload16(const void* g, void* l) {
  __builtin_amdgcn_global_load_lds((__attribute__((address_space(1))) void*)g,
                                   (__attribute__((address_space(3))) void*)l, 16, 0, 0);
}

// ---------------- x fp32 -> bf16 ----------------
__global__ __launch_bounds__(256) void cvt_x_kernel(const float* __restrict__ x,
                                                    unsigned short* __restrict__ xb) {
  int i = blockIdx.x * 256 + threadIdx.x;
  float4 v = reinterpret_cast<const float4*>(x)[i];
  u16x4 o;
  o[0] = f2bf(v.x); o[1] = f2bf(v.y); o[2] = f2bf(v.z); o[3] = f2bf(v.w);
  reinterpret_cast<u16x4*>(xb)[i] = o;
}

// ---------------- router: top-2 (idx, weight) per token ----------------
__global__ __launch_bounds__(256) void router_kernel(const float* __restrict__ x,
                                                     const float* __restrict__ gw,
                                                     int* __restrict__ ti,
                                                     float* __restrict__ tw) {
  int t = blockIdx.x * 4 + (threadIdx.x >> 6);
  int lane = threadIdx.x & 63;
  const float* xp = x + (size_t)t * D_DIM;
  float xv[16];
  #pragma unroll
  for (int i = 0; i < 16; ++i) xv[i] = xp[lane + i * 64];
  float logit[E_EXP];
  #pragma unroll
  for (int e = 0; e < E_EXP; ++e) {
    const float* wp = gw + (size_t)e * D_DIM;
    float s = 0.f;
    #pragma unroll
    for (int i = 0; i < 16; ++i) s += xv[i] * wp[lane + i * 64];
    #pragma unroll
    for (int o = 32; o; o >>= 1) s += __shfl_xor(s, o);
    logit[e] = s;
  }
  float mx = logit[0];
  #pragma unroll
  for (int e = 1; e < E_EXP; ++e) mx = fmaxf(mx, logit[e]);
  float p[E_EXP], sum = 0.f;
  #pragma unroll
  for (int e = 0; e < E_EXP; ++e) { p[e] = __expf(logit[e] - mx); sum += p[e]; }
  int i1 = 0; float p1 = p[0];
  #pragma unroll
  for (int e = 1; e < E_EXP; ++e) if (p[e] > p1) { p1 = p[e]; i1 = e; }
  int i2 = -1; float p2 = -1.f;
  #pragma unroll
  for (int e = 0; e < E_EXP; ++e) if (e != i1 && p[e] > p2) { p2 = p[e]; i2 = e; }
  float P1 = p1 / sum, P2 = p2 / sum;
  float denom = P1 + P2 + 1e-8f;
  if (lane == 0) {
    ti[2 * t] = i1; ti[2 * t + 1] = i2;
    tw[2 * t] = P1 / denom; tw[2 * t + 1] = P2 / denom;
  }
}

__global__ void zero_cnt_kernel(int* cnt) { if (threadIdx.x < E_EXP) cnt[threadIdx.x] = 0; }

__global__ __launch_bounds__(256) void assign_kernel(const int* __restrict__ ti,
                                                     const float* __restrict__ tw,
                                                     int* __restrict__ cnt,
                                                     int* __restrict__ list,
                                                     float* __restrict__ wl,
                                                     int* __restrict__ sl, int cap) {
  int t = blockIdx.x * 256 + threadIdx.x;
  #pragma unroll
  for (int j = 0; j < 2; ++j) {
    int e = ti[2 * t + j];
    float w = tw[2 * t + j];
    int slot = atomicAdd(&cnt[e], 1);
    sl[2 * t + j] = slot;
    if (slot < cap) { list[e * cap + slot] = t; wl[e * cap + slot] = w; }
  }
}

// ---- transpose gate_up: w[k][col] -> wT[n][k] bf16, gate/up INTERLEAVED ----
__global__ __launch_bounds__(256) void transpose_gu_kernel(
    const float* __restrict__ sgu, const float* __restrict__ egu,
    unsigned short* __restrict__ wT) {
  int e = blockIdx.z;
  const float* w = (e == 0) ? sgu : egu + (size_t)(e - 1) * D_DIM * TWO_I;
  unsigned short* o = wT + (size_t)e * NP2 * D_DIM;
  int k0 = blockIdx.x * 64, n0 = blockIdx.y * 32;
  __shared__ unsigned short lds[32][72];
  int tid = threadIdx.x;
  int nn = tid & 31, kr = tid >> 5;
  int n = n0 + nn;
  int hc = n >> 1;
  int src = (hc < I_DIM) ? ((n & 1) ? (I_DIM + hc) : hc) : -1;
  #pragma unroll
  for (int i = 0; i < 8; ++i) {
    int k = k0 + kr + i * 8;
    float f = (src >= 0) ? w[(size_t)k * TWO_I + src] : 0.f;
    lds[nn][kr + i * 8] = f2bf(f);
  }
  __syncthreads();
  int nr = tid >> 3, kc = (tid & 7) * 8;
  u16x8 v;
  #pragma unroll
  for (int j = 0; j < 8; ++j) v[j] = lds[nr][kc + j];
  *reinterpret_cast<u16x8*>(&o[(size_t)(n0 + nr) * D_DIM + k0 + kc]) = v;
}

// ---- transpose down: wd[k][n] -> wT[n][k] bf16, k padded to 1024 ----
__global__ __launch_bounds__(256) void transpose_d_kernel(
    const float* __restrict__ sdn, const float* __restrict__ edn,
    unsigned short* __restrict__ wT) {
  int e = blockIdx.z;
  const float* w = (e == 0) ? sdn : edn + (size_t)(e - 1) * I_DIM * D_DIM;
  unsigned short* o = wT + (size_t)e * D_DIM * IP;
  int k0 = blockIdx.x * 64, n0 = blockIdx.y * 32;
  __shared__ unsigned short lds[32][72];
  int tid = threadIdx.x;
  int nn = tid & 31, kr = tid >> 5;
  #pragma unroll
  for (int i = 0; i < 8; ++i) {
    int k = k0 + kr + i * 8;
    float f = (k < I_DIM) ? w[(size_t)k * D_DIM + n0 + nn] : 0.f;
    lds[nn][kr + i * 8] = f2bf(f);
  }
  __syncthreads();
  int nr = tid >> 3, kc = (tid & 7) * 8;
  u16x8 v;
  #pragma unroll
  for (int j = 0; j < 8; ++j) v[j] = lds[nr][kc + j];
  *reinterpret_cast<u16x8*>(&o[(size_t)(n0 + nr) * IP + k0 + kc]) = v;
}

// ------- GEMM1+SwiGLU: 256x256, BK=64, 512 thr, 2-phase DOUBLE-BUFFER -------
__global__ __launch_bounds__(512) void gemm1_kernel(
    const unsigned short* __restrict__ xb,
    const unsigned short* __restrict__ wTgu,
    unsigned short* __restrict__ h_sh,
    unsigned short* __restrict__ h_g,
    const int* __restrict__ list, const int* __restrict__ cnt, int cap) {
  const int orig = blockIdx.x;
  const int wg = (orig & 7) * (gridDim.x >> 3) + (orig >> 3);   // bijective, 640%8==0
  int e, mb, nb;
  if (wg < 128) { e = 0; mb = wg >> 3; nb = wg & 7; }
  else { int r = wg - 128; e = 1 + (r >> 6); int rem = r & 63; mb = rem >> 3; nb = rem & 7; }
  const int m0 = mb * 256, n0 = nb * 256;
  int count = T_TOK;
  unsigned short* h = h_sh;
  if (e > 0) {
    count = min(cnt[e - 1], cap);
    if (m0 >= count) return;
    h = h_g + (size_t)(e - 1) * cap * IP;
  }
  const unsigned short* w = wTgu + (size_t)e * NP2 * D_DIM;

  __shared__ __align__(16) unsigned short a_lds[2][256 * 64];   // 64 KB
  __shared__ __align__(16) unsigned short b_lds[2][256 * 64];   // 64 KB
  const int tid = threadIdx.x;
  const int wave = tid >> 6, lane = tid & 63;
  const int mw = (wave >> 2) * 128, nw = (wave & 3) * 64;
  const int fr = lane & 15, fq = lane >> 4;
  const int srow = tid >> 3;
  const int sk = (tid & 7) * 8;

  size_t arow[4], brow[4];
  #pragma unroll
  for (int c = 0; c < 4; ++c) {
    int rr = m0 + 64 * c + srow;
    if (e > 0) rr = list[(e - 1) * cap + min(rr, count - 1)];
    arow[c] = (size_t)rr * D_DIM;
    brow[c] = (size_t)(n0 + 64 * c + srow) * D_DIM;
  }

  f32x4 acc[8][4];
  #pragma unroll
  for (int m = 0; m < 8; ++m)
    #pragma unroll
    for (int n = 0; n < 4; ++n) acc[m][n] = (f32x4)0.f;

  auto stage = [&](int buf, int k0) {
    #pragma unroll
    for (int c = 0; c < 4; ++c) {
      gload16(xb + arow[c] + k0 + sk, &a_lds[buf][(64 * c + srow) * 64 + sk]);
      gload16(w + brow[c] + k0 + sk, &b_lds[buf][(64 * c + srow) * 64 + sk]);
    }
  };

  stage(0, 0);
  __syncthreads();                       // drains vmcnt(0): buf0 ready
  int cur = 0;
  for (int t = 0; t < D_DIM / 64; ++t) {
    if (t + 1 < D_DIM / 64) stage(cur ^ 1, (t + 1) * 64);   // issue BEFORE compute
    #pragma unroll
    for (int kk = 0; kk < 2; ++kk) {
      bf16x8 av[8], bv[4];
      #pragma unroll
      for (int m = 0; m < 8; ++m)
        av[m] = *reinterpret_cast<const bf16x8*>(&a_lds[cur][(mw + m * 16 + fr) * 64 + kk * 32 + fq * 8]);
      #pragma unroll
      for (int n = 0; n < 4; ++n)
        bv[n] = *reinterpret_cast<const bf16x8*>(&b_lds[cur][(nw + n * 16 + fr) * 64 + kk * 32 + fq * 8]);
      #pragma unroll
      for (int m = 0; m < 8; ++m)
        #pragma unroll
        for (int n = 0; n < 4; ++n)
          acc[m][n] = __builtin_amdgcn_mfma_f32_16x16x32_bf16(av[m], bv[n], acc[m][n], 0, 0, 0);
    }
    __syncthreads();                     // one barrier/K-step; drains vmcnt for next buf
    cur ^= 1;
  }
  // epilogue: even B-row = gate, odd = up (same h-col); pair via shfl_xor(1)
  const bool isGate = !(fr & 1);
  const int hcb = (n0 + nw) >> 1;
  #pragma unroll
  for (int m = 0; m < 8; ++m)
    #pragma unroll
    for (int n = 0; n < 4; ++n)
      #pragma unroll
      for (int q = 0; q < 4; ++q) {
        float v = acc[m][n][q];
        float pt = __shfl_xor(v, 1);
        if (isGate) {
          float hv = (v / (1.f + __expf(-v))) * pt;
          int trow = m0 + mw + m * 16 + fq * 4 + q;
          h[(size_t)trow * IP + hcb + n * 8 + (fr >> 1)] = f2bf(hv);
        }
      }
}

// ------- GEMM2: shared -> out (store); routed -> y_g[e][slot] fp32 (wgt folded) -------
__global__ __launch_bounds__(512) void gemm2_kernel(
    const unsigned short* __restrict__ h_sh,
    const unsigned short* __restrict__ h_g,
    const unsigned short* __restrict__ wTd,
    float* __restrict__ out, float* __restrict__ y_g,
    const float* __restrict__ wl, const int* __restrict__ cnt, int cap) {
  const int orig = blockIdx.x;
  const int wg = (orig & 7) * (gridDim.x >> 3) + (orig >> 3);   // 320%8==0
  int e, mb, nb;
  if (wg < 64) { e = -1; mb = wg >> 2; nb = wg & 3; }
  else { int r = wg - 64; e = r >> 5; int rem = r & 31; mb = rem >> 2; nb = rem & 3; }
  const int m0 = mb * 256, n0 = nb * 256;
  int count = T_TOK;
  const unsigned short* A = h_sh;
  if (e >= 0) {
    count = min(cnt[e], cap);
    if (m0 >= count) return;
    A = h_g + (size_t)e * cap * IP;
  }
  const unsigned short* B = wTd + (size_t)(e + 1) * D_DIM * IP;

  __shared__ __align__(16) unsigned short a_lds[2][256 * 64];
  __shared__ __align__(16) unsigned short b_lds[2][256 * 64];
  const int tid = threadIdx.x;
  const int wave = tid >> 6, lane = tid & 63;
  const int mw = (wave >> 2) * 128, nw = (wave & 3) * 64;
  const int fr = lane & 15, fq = lane >> 4;
  const int srow = tid >> 3;
  const int sk = (tid & 7) * 8;

  f32x4 acc[8][4];
  #pragma unroll
  for (int m = 0; m < 8; ++m)
    #pragma unroll
    for (int n = 0; n < 4; ++n) acc[m][n] = (f32x4)0.f;

  auto stage = [&](int buf, int k0) {
    #pragma unroll
    for (int c = 0; c < 4; ++c) {
      gload16(A + (size_t)(m0 + 64 * c + srow) * IP + k0 + sk,
              &a_lds[buf][(64 * c + srow) * 64 + sk]);
      gload16(B + (size_t)(n0 + 64 * c + srow) * IP + k0 + sk,
              &b_lds[buf][(64 * c + srow) * 64 + sk]);
    }
  };
  stage(0, 0);
  __syncthreads();
  int cur = 0;
  for (int t = 0; t < IP / 64; ++t) {
    if (t + 1 < IP / 64) stage(cur ^ 1, (t + 1) * 64);
    #pragma unroll
    for (int kk = 0; kk < 2; ++kk) {
      bf16x8 av[8], bv[4];
      #pragma unroll
      for (int m = 0; m < 8; ++m)
        av[m] = *reinterpret_cast<const bf16x8*>(&a_lds[cur][(mw + m * 16 + fr) * 64 + kk * 32 + fq * 8]);
      #pragma unroll
      for (int n = 0; n < 4; ++n)
        bv[n] = *reinterpret_cast<const bf16x8*>(&b_lds[cur][(nw + n * 16 + fr) * 64 + kk * 32 + fq * 8]);
      #pragma unroll
      for (int m = 0; m < 8; ++m)
        #pragma unroll
        for (int n = 0; n < 4; ++n)
          acc[m][n] = __builtin_amdgcn_mfma_f32_16x16x32_bf16(av[m], bv[n], acc[m][n], 0, 0, 0);
    }
    __syncthreads();
    cur ^= 1;
  }
  #pragma unroll
  for (int m = 0; m < 8; ++m)
    #pragma unroll
    for (int q = 0; q < 4; ++q) {
      int slot = m0 + mw + m * 16 + fq * 4 + q;
      if (slot < count) {
        if (e < 0) {
          #pragma unroll
          for (int n = 0; n < 4; ++n)
            out[(size_t)slot * D_DIM + n0 + nw + n * 16 + fr] = acc[m][n][q];
        } else {
          float wgt = wl[e * cap + slot];
          #pragma unroll
          for (int n = 0; n < 4; ++n)
            y_g[((size_t)e * cap + slot) * D_DIM + n0 + nw + n * 16 + fr] = wgt * acc[m][n][q];
        }
      }
    }
}

// ------- combine: out[t] += y_g[e1][s1] + y_g[e2][s2] -------
__global__ __launch_bounds__(256) void combine_kernel(
    float* __restrict__ out, const float* __restrict__ y_g,
    const int* __restrict__ ti, const int* __restrict__ sl,
    const int* __restrict__ cnt, int cap) {
  int t = blockIdx.x;
  int c = threadIdx.x * 4;
  float4 v = *reinterpret_cast<float4*>(&out[(size_t)t * D_DIM + c]);
  #pragma unroll
  for (int j = 0; j < 2; ++j) {
    int e = ti[2 * t + j], s = sl[2 * t + j];
    if (s < cap) {
      float4 y = *reinterpret_cast<const float4*>(&y_g[((size_t)e * cap + s) * D_DIM + c]);
      v.x += y.x; v.y += y.y; v.z += y.z; v.w += y.w;
    }
  }
  *reinterpret_cast<float4*>(&out[(size_t)t * D_DIM + c]) = v;
}

extern "C" void kernel_launch(void* const* d_in, const int* in_sizes, int n_in,
                              void* d_out, int out_size, void* d_ws, size_t ws_size,
                              hipStream_t stream) {
  const float* x   = (const float*)d_in[0];
  const float* gw  = (const float*)d_in[1];
  const float* sgu = (const float*)d_in[2];
  const float* sdn = (const float*)d_in[3];
  const float* egu = (const float*)d_in[4];
  const float* edn = (const float*)d_in[5];
  float* out = (float*)d_out;

  char* p = (char*)d_ws;
  unsigned short* xb   = (unsigned short*)p; p += (size_t)T_TOK * D_DIM * 2;
  unsigned short* wTgu = (unsigned short*)p; p += (size_t)9 * NP2 * D_DIM * 2;
  unsigned short* wTd  = (unsigned short*)p; p += (size_t)9 * D_DIM * IP * 2;
  unsigned short* h_sh = (unsigned short*)p; p += (size_t)T_TOK * IP * 2;

  size_t fixed_tail = (size_t)T_TOK * 2 * (4 + 4 + 4) + 64 + 256;
  size_t used = (size_t)(p - (char*)d_ws) + fixed_tail;
  size_t per_cap = (size_t)E_EXP * (IP * 2 + D_DIM * 4 + 4 + 4);  // h_g + y_g + list + wl
  long avail = (long)ws_size - (long)used;
  int cap = (int)(avail > 0 ? avail / (long)per_cap : 0);
  cap &= ~255;
  if (cap > 2048) cap = 2048;
  if (cap < 1536) cap = 1536;

  unsigned short* h_g = (unsigned short*)p; p += (size_t)E_EXP * cap * IP * 2;
  float* y_g  = (float*)p; p += (size_t)E_EXP * cap * D_DIM * 4;
  int*   ti   = (int*)p;   p += (size_t)T_TOK * 2 * 4;
  float* tw   = (float*)p; p += (size_t)T_TOK * 2 * 4;
  int*   sl   = (int*)p;   p += (size_t)T_TOK * 2 * 4;
  int*   list = (int*)p;   p += (size_t)E_EXP * cap * 4;
  float* wl   = (float*)p; p += (size_t)E_EXP * cap * 4;
  int*   cnt  = (int*)p;

  cvt_x_kernel<<<(T_TOK * D_DIM) / (4 * 256), 256, 0, stream>>>(x, xb);
  router_kernel<<<T_TOK / 4, 256, 0, stream>>>(x, gw, ti, tw);
  zero_cnt_kernel<<<1, 64, 0, stream>>>(cnt);
  assign_kernel<<<T_TOK / 256, 256, 0, stream>>>(ti, tw, cnt, list, wl, sl, cap);
  transpose_gu_kernel<<<dim3(D_DIM / 64, NP2 / 32, 9), 256, 0, stream>>>(sgu, egu, wTgu);
  transpose_d_kernel<<<dim3(IP / 64, D_DIM / 32, 9), 256, 0, stream>>>(sdn, edn, wTd);

  gemm1_kernel<<<128 + E_EXP * 64, 512, 0, stream>>>(xb, wTgu, h_sh, h_g, list, cnt, cap);
  gemm2_kernel<<<64 + E_EXP * 32, 512, 0, stream>>>(h_sh, h_g, wTd, out, y_g, wl, cnt, cap);
  combine_kernel<<<T_TOK, 256, 0, stream>>>(out, y_g, ti, sl, cnt, cap);
}

// Round 8
// 446.435 us; speedup vs baseline: 1.1316x; 1.0337x over previous
//
#include <hip/hip_runtime.h>
#include <hip/hip_bf16.h>
#include <stdint.h>

#define T_TOK 4096
#define D_DIM 1024
#define E_EXP 8
#define I_DIM 938
#define TWO_I 1876
#define NP2 2048       // interleaved gate/up rows: row 2c = gate col c, 2c+1 = up col c
#define IP 1024        // padded I

typedef __attribute__((ext_vector_type(8))) short bf16x8;
typedef __attribute__((ext_vector_type(4))) float f32x4;
typedef __attribute__((ext_vector_type(8))) unsigned short u16x8;
typedef __attribute__((ext_vector_type(4))) unsigned short u16x4;

static __device__ __forceinline__ unsigned short f2bf(float f) {
  union { float f; uint32_t u; } v; v.f = f;
  uint32_t r = v.u + 0x7fffu + ((v.u >> 16) & 1u);
  return (unsigned short)(r >> 16);
}
static __device__ __forceinline__ void gload16(const void* g, void* l) {
  __builtin_amdgcn_global_load_lds((__attribute__((address_space(1))) void*)g,
                                   (__attribute__((address_space(3))) void*)l, 16, 0, 0);
}

// ---------------- x fp32 -> bf16 ----------------
__global__ __launch_bounds__(256) void cvt_x_kernel(const float* __restrict__ x,
                                                    unsigned short* __restrict__ xb) {
  int i = blockIdx.x * 256 + threadIdx.x;
  float4 v = reinterpret_cast<const float4*>(x)[i];
  u16x4 o;
  o[0] = f2bf(v.x); o[1] = f2bf(v.y); o[2] = f2bf(v.z); o[3] = f2bf(v.w);
  reinterpret_cast<u16x4*>(xb)[i] = o;
}

// ---------------- router: top-2 (idx, weight) per token ----------------
__global__ __launch_bounds__(256) void router_kernel(const float* __restrict__ x,
                                                     const float* __restrict__ gw,
                                                     int* __restrict__ ti,
                                                     float* __restrict__ tw) {
  int t = blockIdx.x * 4 + (threadIdx.x >> 6);
  int lane = threadIdx.x & 63;
  const float* xp = x + (size_t)t * D_DIM;
  float xv[16];
  #pragma unroll
  for (int i = 0; i < 16; ++i) xv[i] = xp[lane + i * 64];
  float logit[E_EXP];
  #pragma unroll
  for (int e = 0; e < E_EXP; ++e) {
    const float* wp = gw + (size_t)e * D_DIM;
    float s = 0.f;
    #pragma unroll
    for (int i = 0; i < 16; ++i) s += xv[i] * wp[lane + i * 64];
    #pragma unroll
    for (int o = 32; o; o >>= 1) s += __shfl_xor(s, o);
    logit[e] = s;
  }
  float mx = logit[0];
  #pragma unroll
  for (int e = 1; e < E_EXP; ++e) mx = fmaxf(mx, logit[e]);
  float p[E_EXP], sum = 0.f;
  #pragma unroll
  for (int e = 0; e < E_EXP; ++e) { p[e] = __expf(logit[e] - mx); sum += p[e]; }
  int i1 = 0; float p1 = p[0];
  #pragma unroll
  for (int e = 1; e < E_EXP; ++e) if (p[e] > p1) { p1 = p[e]; i1 = e; }
  int i2 = -1; float p2 = -1.f;
  #pragma unroll
  for (int e = 0; e < E_EXP; ++e) if (e != i1 && p[e] > p2) { p2 = p[e]; i2 = e; }
  float P1 = p1 / sum, P2 = p2 / sum;
  float denom = P1 + P2 + 1e-8f;
  if (lane == 0) {
    ti[2 * t] = i1; ti[2 * t + 1] = i2;
    tw[2 * t] = P1 / denom; tw[2 * t + 1] = P2 / denom;
  }
}

__global__ void zero_cnt_kernel(int* cnt) { if (threadIdx.x < E_EXP) cnt[threadIdx.x] = 0; }

__global__ __launch_bounds__(256) void assign_kernel(const int* __restrict__ ti,
                                                     const float* __restrict__ tw,
                                                     int* __restrict__ cnt,
                                                     int* __restrict__ list,
                                                     float* __restrict__ wl,
                                                     int* __restrict__ sl, int cap) {
  int t = blockIdx.x * 256 + threadIdx.x;
  #pragma unroll
  for (int j = 0; j < 2; ++j) {
    int e = ti[2 * t + j];
    float w = tw[2 * t + j];
    int slot = atomicAdd(&cnt[e], 1);
    sl[2 * t + j] = slot;
    if (slot < cap) { list[e * cap + slot] = t; wl[e * cap + slot] = w; }
  }
}

// ---- transpose gate_up: w[k][col] -> wT[n][k] bf16, gate/up INTERLEAVED ----
__global__ __launch_bounds__(256) void transpose_gu_kernel(
    const float* __restrict__ sgu, const float* __restrict__ egu,
    unsigned short* __restrict__ wT) {
  int e = blockIdx.z;
  const float* w = (e == 0) ? sgu : egu + (size_t)(e - 1) * D_DIM * TWO_I;
  unsigned short* o = wT + (size_t)e * NP2 * D_DIM;
  int k0 = blockIdx.x * 64, n0 = blockIdx.y * 32;
  __shared__ unsigned short lds[32][72];
  int tid = threadIdx.x;
  int nn = tid & 31, kr = tid >> 5;
  int n = n0 + nn;
  int hc = n >> 1;
  int src = (hc < I_DIM) ? ((n & 1) ? (I_DIM + hc) : hc) : -1;
  #pragma unroll
  for (int i = 0; i < 8; ++i) {
    int k = k0 + kr + i * 8;
    float f = (src >= 0) ? w[(size_t)k * TWO_I + src] : 0.f;
    lds[nn][kr + i * 8] = f2bf(f);
  }
  __syncthreads();
  int nr = tid >> 3, kc = (tid & 7) * 8;
  u16x8 v;
  #pragma unroll
  for (int j = 0; j < 8; ++j) v[j] = lds[nr][kc + j];
  *reinterpret_cast<u16x8*>(&o[(size_t)(n0 + nr) * D_DIM + k0 + kc]) = v;
}

// ---- transpose down: wd[k][n] -> wT[n][k] bf16, k padded to 1024 ----
__global__ __launch_bounds__(256) void transpose_d_kernel(
    const float* __restrict__ sdn, const float* __restrict__ edn,
    unsigned short* __restrict__ wT) {
  int e = blockIdx.z;
  const float* w = (e == 0) ? sdn : edn + (size_t)(e - 1) * I_DIM * D_DIM;
  unsigned short* o = wT + (size_t)e * D_DIM * IP;
  int k0 = blockIdx.x * 64, n0 = blockIdx.y * 32;
  __shared__ unsigned short lds[32][72];
  int tid = threadIdx.x;
  int nn = tid & 31, kr = tid >> 5;
  #pragma unroll
  for (int i = 0; i < 8; ++i) {
    int k = k0 + kr + i * 8;
    float f = (k < I_DIM) ? w[(size_t)k * D_DIM + n0 + nn] : 0.f;
    lds[nn][kr + i * 8] = f2bf(f);
  }
  __syncthreads();
  int nr = tid >> 3, kc = (tid & 7) * 8;
  u16x8 v;
  #pragma unroll
  for (int j = 0; j < 8; ++j) v[j] = lds[nr][kc + j];
  *reinterpret_cast<u16x8*>(&o[(size_t)(n0 + nr) * IP + k0 + kc]) = v;
}

// ------- GEMM1+SwiGLU: 256x256, BK=64, dbuf + COUNTED vmcnt (T4) -------
__global__ __launch_bounds__(512) void gemm1_kernel(
    const unsigned short* __restrict__ xb,
    const unsigned short* __restrict__ wTgu,
    unsigned short* __restrict__ h_sh,
    unsigned short* __restrict__ h_g,
    const int* __restrict__ list, const int* __restrict__ cnt, int cap) {
  const int orig = blockIdx.x;
  const int wg = (orig & 7) * (gridDim.x >> 3) + (orig >> 3);   // bijective, 640%8==0
  int e, mb, nb;
  if (wg < 128) { e = 0; mb = wg >> 3; nb = wg & 7; }
  else { int r = wg - 128; e = 1 + (r >> 6); int rem = r & 63; mb = rem >> 3; nb = rem & 7; }
  const int m0 = mb * 256, n0 = nb * 256;
  int count = T_TOK;
  unsigned short* h = h_sh;
  if (e > 0) {
    count = min(cnt[e - 1], cap);
    if (m0 >= count) return;
    h = h_g + (size_t)(e - 1) * cap * IP;
  }
  const unsigned short* w = wTgu + (size_t)e * NP2 * D_DIM;

  __shared__ __align__(16) unsigned short a_lds[2][256 * 64];   // 64 KB
  __shared__ __align__(16) unsigned short b_lds[2][256 * 64];   // 64 KB
  const int tid = threadIdx.x;
  const int wave = tid >> 6, lane = tid & 63;
  const int mw = (wave >> 2) * 128, nw = (wave & 3) * 64;
  const int fr = lane & 15, fq = lane >> 4;
  const int srow = tid >> 3;
  const int sk = (tid & 7) * 8;

  size_t arow[4], brow[4];
  #pragma unroll
  for (int c = 0; c < 4; ++c) {
    int rr = m0 + 64 * c + srow;
    if (e > 0) rr = list[(e - 1) * cap + min(rr, count - 1)];
    arow[c] = (size_t)rr * D_DIM;
    brow[c] = (size_t)(n0 + 64 * c + srow) * D_DIM;
  }

  f32x4 acc[8][4];
  #pragma unroll
  for (int m = 0; m < 8; ++m)
    #pragma unroll
    for (int n = 0; n < 4; ++n) acc[m][n] = (f32x4)0.f;

  auto stage = [&](int buf, int k0) {   // 8 gload_lds per thread
    #pragma unroll
    for (int c = 0; c < 4; ++c) {
      gload16(xb + arow[c] + k0 + sk, &a_lds[buf][(64 * c + srow) * 64 + sk]);
      gload16(w + brow[c] + k0 + sk, &b_lds[buf][(64 * c + srow) * 64 + sk]);
    }
  };

  stage(0, 0);                        // 8 outstanding (buf0)
  int cur = 0;
  for (int t = 0; t < D_DIM / 64; ++t) {
    if (t + 1 < D_DIM / 64) {
      stage(cur ^ 1, (t + 1) * 64);   // +8 in flight (buf cur^1)
      asm volatile("s_waitcnt vmcnt(8)" ::: "memory");   // oldest 8 (cur) landed
    } else {
      asm volatile("s_waitcnt vmcnt(0)" ::: "memory");   // tail: drain cur
    }
    __builtin_amdgcn_s_barrier();     // all waves' cur-loads visible
    #pragma unroll
    for (int kk = 0; kk < 2; ++kk) {
      bf16x8 av[8], bv[4];
      #pragma unroll
      for (int m = 0; m < 8; ++m)
        av[m] = *reinterpret_cast<const bf16x8*>(&a_lds[cur][(mw + m * 16 + fr) * 64 + kk * 32 + fq * 8]);
      #pragma unroll
      for (int n = 0; n < 4; ++n)
        bv[n] = *reinterpret_cast<const bf16x8*>(&b_lds[cur][(nw + n * 16 + fr) * 64 + kk * 32 + fq * 8]);
      #pragma unroll
      for (int m = 0; m < 8; ++m)
        #pragma unroll
        for (int n = 0; n < 4; ++n)
          acc[m][n] = __builtin_amdgcn_mfma_f32_16x16x32_bf16(av[m], bv[n], acc[m][n], 0, 0, 0);
    }
    __builtin_amdgcn_s_barrier();     // done reading cur before it is restaged
    cur ^= 1;
  }
  // epilogue: even B-row = gate, odd = up (same h-col); pair via shfl_xor(1)
  const bool isGate = !(fr & 1);
  const int hcb = (n0 + nw) >> 1;
  #pragma unroll
  for (int m = 0; m < 8; ++m)
    #pragma unroll
    for (int n = 0; n < 4; ++n)
      #pragma unroll
      for (int q = 0; q < 4; ++q) {
        float v = acc[m][n][q];
        float pt = __shfl_xor(v, 1);
        if (isGate) {
          float hv = (v / (1.f + __expf(-v))) * pt;
          int trow = m0 + mw + m * 16 + fq * 4 + q;
          h[(size_t)trow * IP + hcb + n * 8 + (fr >> 1)] = f2bf(hv);
        }
      }
}

// ------- GEMM2: shared -> out (store); routed -> y_g (wgt folded); counted vmcnt -------
__global__ __launch_bounds__(512) void gemm2_kernel(
    const unsigned short* __restrict__ h_sh,
    const unsigned short* __restrict__ h_g,
    const unsigned short* __restrict__ wTd,
    float* __restrict__ out, float* __restrict__ y_g,
    const float* __restrict__ wl, const int* __restrict__ cnt, int cap) {
  const int orig = blockIdx.x;
  const int wg = (orig & 7) * (gridDim.x >> 3) + (orig >> 3);   // 320%8==0
  int e, mb, nb;
  if (wg < 64) { e = -1; mb = wg >> 2; nb = wg & 3; }
  else { int r = wg - 64; e = r >> 5; int rem = r & 31; mb = rem >> 2; nb = rem & 3; }
  const int m0 = mb * 256, n0 = nb * 256;
  int count = T_TOK;
  const unsigned short* A = h_sh;
  if (e >= 0) {
    count = min(cnt[e], cap);
    if (m0 >= count) return;
    A = h_g + (size_t)e * cap * IP;
  }
  const unsigned short* B = wTd + (size_t)(e + 1) * D_DIM * IP;

  __shared__ __align__(16) unsigned short a_lds[2][256 * 64];
  __shared__ __align__(16) unsigned short b_lds[2][256 * 64];
  const int tid = threadIdx.x;
  const int wave = tid >> 6, lane = tid & 63;
  const int mw = (wave >> 2) * 128, nw = (wave & 3) * 64;
  const int fr = lane & 15, fq = lane >> 4;
  const int srow = tid >> 3;
  const int sk = (tid & 7) * 8;

  f32x4 acc[8][4];
  #pragma unroll
  for (int m = 0; m < 8; ++m)
    #pragma unroll
    for (int n = 0; n < 4; ++n) acc[m][n] = (f32x4)0.f;

  auto stage = [&](int buf, int k0) {
    #pragma unroll
    for (int c = 0; c < 4; ++c) {
      gload16(A + (size_t)(m0 + 64 * c + srow) * IP + k0 + sk,
              &a_lds[buf][(64 * c + srow) * 64 + sk]);
      gload16(B + (size_t)(n0 + 64 * c + srow) * IP + k0 + sk,
              &b_lds[buf][(64 * c + srow) * 64 + sk]);
    }
  };
  stage(0, 0);
  int cur = 0;
  for (int t = 0; t < IP / 64; ++t) {
    if (t + 1 < IP / 64) {
      stage(cur ^ 1, (t + 1) * 64);
      asm volatile("s_waitcnt vmcnt(8)" ::: "memory");
    } else {
      asm volatile("s_waitcnt vmcnt(0)" ::: "memory");
    }
    __builtin_amdgcn_s_barrier();
    #pragma unroll
    for (int kk = 0; kk < 2; ++kk) {
      bf16x8 av[8], bv[4];
      #pragma unroll
      for (int m = 0; m < 8; ++m)
        av[m] = *reinterpret_cast<const bf16x8*>(&a_lds[cur][(mw + m * 16 + fr) * 64 + kk * 32 + fq * 8]);
      #pragma unroll
      for (int n = 0; n < 4; ++n)
        bv[n] = *reinterpret_cast<const bf16x8*>(&b_lds[cur][(nw + n * 16 + fr) * 64 + kk * 32 + fq * 8]);
      #pragma unroll
      for (int m = 0; m < 8; ++m)
        #pragma unroll
        for (int n = 0; n < 4; ++n)
          acc[m][n] = __builtin_amdgcn_mfma_f32_16x16x32_bf16(av[m], bv[n], acc[m][n], 0, 0, 0);
    }
    __builtin_amdgcn_s_barrier();
    cur ^= 1;
  }
  #pragma unroll
  for (int m = 0; m < 8; ++m)
    #pragma unroll
    for (int q = 0; q < 4; ++q) {
      int slot = m0 + mw + m * 16 + fq * 4 + q;
      if (slot < count) {
        if (e < 0) {
          #pragma unroll
          for (int n = 0; n < 4; ++n)
            out[(size_t)slot * D_DIM + n0 + nw + n * 16 + fr] = acc[m][n][q];
        } else {
          float wgt = wl[e * cap + slot];
          #pragma unroll
          for (int n = 0; n < 4; ++n)
            y_g[((size_t)e * cap + slot) * D_DIM + n0 + nw + n * 16 + fr] = wgt * acc[m][n][q];
        }
      }
    }
}

// ------- combine: out[t] += y_g[e1][s1] + y_g[e2][s2] -------
__global__ __launch_bounds__(256) void combine_kernel(
    float* __restrict__ out, const float* __restrict__ y_g,
    const int* __restrict__ ti, const int* __restrict__ sl,
    const int* __restrict__ cnt, int cap) {
  int t = blockIdx.x;
  int c = threadIdx.x * 4;
  float4 v = *reinterpret_cast<float4*>(&out[(size_t)t * D_DIM + c]);
  #pragma unroll
  for (int j = 0; j < 2; ++j) {
    int e = ti[2 * t + j], s = sl[2 * t + j];
    if (s < cap) {
      float4 y = *reinterpret_cast<const float4*>(&y_g[((size_t)e * cap + s) * D_DIM + c]);
      v.x += y.x; v.y += y.y; v.z += y.z; v.w += y.w;
    }
  }
  *reinterpret_cast<float4*>(&out[(size_t)t * D_DIM + c]) = v;
}

extern "C" void kernel_launch(void* const* d_in, const int* in_sizes, int n_in,
                              void* d_out, int out_size, void* d_ws, size_t ws_size,
                              hipStream_t stream) {
  const float* x   = (const float*)d_in[0];
  const float* gw  = (const float*)d_in[1];
  const float* sgu = (const float*)d_in[2];
  const float* sdn = (const float*)d_in[3];
  const float* egu = (const float*)d_in[4];
  const float* edn = (const float*)d_in[5];
  float* out = (float*)d_out;

  char* p = (char*)d_ws;
  unsigned short* xb   = (unsigned short*)p; p += (size_t)T_TOK * D_DIM * 2;
  unsigned short* wTgu = (unsigned short*)p; p += (size_t)9 * NP2 * D_DIM * 2;
  unsigned short* wTd  = (unsigned short*)p; p += (size_t)9 * D_DIM * IP * 2;
  unsigned short* h_sh = (unsigned short*)p; p += (size_t)T_TOK * IP * 2;

  size_t fixed_tail = (size_t)T_TOK * 2 * (4 + 4 + 4) + 64 + 256;
  size_t used = (size_t)(p - (char*)d_ws) + fixed_tail;
  size_t per_cap = (size_t)E_EXP * (IP * 2 + D_DIM * 4 + 4 + 4);  // h_g + y_g + list + wl
  long avail = (long)ws_size - (long)used;
  int cap = (int)(avail > 0 ? avail / (long)per_cap : 0);
  cap &= ~255;
  if (cap > 2048) cap = 2048;
  if (cap < 1536) cap = 1536;

  unsigned short* h_g = (unsigned short*)p; p += (size_t)E_EXP * cap * IP * 2;
  float* y_g  = (float*)p; p += (size_t)E_EXP * cap * D_DIM * 4;
  int*   ti   = (int*)p;   p += (size_t)T_TOK * 2 * 4;
  float* tw   = (float*)p; p += (size_t)T_TOK * 2 * 4;
  int*   sl   = (int*)p;   p += (size_t)T_TOK * 2 * 4;
  int*   list = (int*)p;   p += (size_t)E_EXP * cap * 4;
  float* wl   = (float*)p; p += (size_t)E_EXP * cap * 4;
  int*   cnt  = (int*)p;

  cvt_x_kernel<<<(T_TOK * D_DIM) / (4 * 256), 256, 0, stream>>>(x, xb);
  router_kernel<<<T_TOK / 4, 256, 0, stream>>>(x, gw, ti, tw);
  zero_cnt_kernel<<<1, 64, 0, stream>>>(cnt);
  assign_kernel<<<T_TOK / 256, 256, 0, stream>>>(ti, tw, cnt, list, wl, sl, cap);
  transpose_gu_kernel<<<dim3(D_DIM / 64, NP2 / 32, 9), 256, 0, stream>>>(sgu, egu, wTgu);
  transpose_d_kernel<<<dim3(IP / 64, D_DIM / 32, 9), 256, 0, stream>>>(sdn, edn, wTd);

  gemm1_kernel<<<128 + E_EXP * 64, 512, 0, stream>>>(xb, wTgu, h_sh, h_g, list, cnt, cap);
  gemm2_kernel<<<64 + E_EXP * 32, 512, 0, stream>>>(h_sh, h_g, wTd, out, y_g, wl, cnt, cap);
  combine_kernel<<<T_TOK, 256, 0, stream>>>(out, y_g, ti, sl, cnt, cap);
}

// Round 9
// 415.687 us; speedup vs baseline: 1.2153x; 1.0740x over previous
//
#include <hip/hip_runtime.h>
#include <hip/hip_bf16.h>
#include <stdint.h>

#define T_TOK 4096
#define D_DIM 1024
#define E_EXP 8
#define I_DIM 938
#define TWO_I 1876
#define NP2 2048       // interleaved gate/up rows: row 2c = gate col c, 2c+1 = up col c
#define IP 1024        // padded I

typedef __attribute__((ext_vector_type(8))) short bf16x8;
typedef __attribute__((ext_vector_type(4))) float f32x4;
typedef __attribute__((ext_vector_type(8))) unsigned short u16x8;
typedef __attribute__((ext_vector_type(4))) unsigned short u16x4;

static __device__ __forceinline__ unsigned short f2bf(float f) {
  union { float f; uint32_t u; } v; v.f = f;
  uint32_t r = v.u + 0x7fffu + ((v.u >> 16) & 1u);
  return (unsigned short)(r >> 16);
}
static __device__ __forceinline__ void gload16(const void* g, void* l) {
  __builtin_amdgcn_global_load_lds((__attribute__((address_space(1))) void*)g,
                                   (__attribute__((address_space(3))) void*)l, 16, 0, 0);
}

// ---------------- x fp32 -> bf16 ----------------
__global__ __launch_bounds__(256) void cvt_x_kernel(const float* __restrict__ x,
                                                    unsigned short* __restrict__ xb) {
  int i = blockIdx.x * 256 + threadIdx.x;
  float4 v = reinterpret_cast<const float4*>(x)[i];
  u16x4 o;
  o[0] = f2bf(v.x); o[1] = f2bf(v.y); o[2] = f2bf(v.z); o[3] = f2bf(v.w);
  reinterpret_cast<u16x4*>(xb)[i] = o;
}

// ---------------- router: top-2 (idx, weight) per token ----------------
__global__ __launch_bounds__(256) void router_kernel(const float* __restrict__ x,
                                                     const float* __restrict__ gw,
                                                     int* __restrict__ ti,
                                                     float* __restrict__ tw) {
  int t = blockIdx.x * 4 + (threadIdx.x >> 6);
  int lane = threadIdx.x & 63;
  const float* xp = x + (size_t)t * D_DIM;
  float xv[16];
  #pragma unroll
  for (int i = 0; i < 16; ++i) xv[i] = xp[lane + i * 64];
  float logit[E_EXP];
  #pragma unroll
  for (int e = 0; e < E_EXP; ++e) {
    const float* wp = gw + (size_t)e * D_DIM;
    float s = 0.f;
    #pragma unroll
    for (int i = 0; i < 16; ++i) s += xv[i] * wp[lane + i * 64];
    #pragma unroll
    for (int o = 32; o; o >>= 1) s += __shfl_xor(s, o);
    logit[e] = s;
  }
  float mx = logit[0];
  #pragma unroll
  for (int e = 1; e < E_EXP; ++e) mx = fmaxf(mx, logit[e]);
  float p[E_EXP], sum = 0.f;
  #pragma unroll
  for (int e = 0; e < E_EXP; ++e) { p[e] = __expf(logit[e] - mx); sum += p[e]; }
  int i1 = 0; float p1 = p[0];
  #pragma unroll
  for (int e = 1; e < E_EXP; ++e) if (p[e] > p1) { p1 = p[e]; i1 = e; }
  int i2 = -1; float p2 = -1.f;
  #pragma unroll
  for (int e = 0; e < E_EXP; ++e) if (e != i1 && p[e] > p2) { p2 = p[e]; i2 = e; }
  float P1 = p1 / sum, P2 = p2 / sum;
  float denom = P1 + P2 + 1e-8f;
  if (lane == 0) {
    ti[2 * t] = i1; ti[2 * t + 1] = i2;
    tw[2 * t] = P1 / denom; tw[2 * t + 1] = P2 / denom;
  }
}

__global__ void zero_cnt_kernel(int* cnt) { if (threadIdx.x < E_EXP) cnt[threadIdx.x] = 0; }

__global__ __launch_bounds__(256) void assign_kernel(const int* __restrict__ ti,
                                                     const float* __restrict__ tw,
                                                     int* __restrict__ cnt,
                                                     int* __restrict__ list,
                                                     float* __restrict__ wl,
                                                     int* __restrict__ sl, int cap) {
  int t = blockIdx.x * 256 + threadIdx.x;
  #pragma unroll
  for (int j = 0; j < 2; ++j) {
    int e = ti[2 * t + j];
    float w = tw[2 * t + j];
    int slot = atomicAdd(&cnt[e], 1);
    sl[2 * t + j] = slot;
    if (slot < cap) { list[e * cap + slot] = t; wl[e * cap + slot] = w; }
  }
}

// ---- transpose gate_up: w[k][col] -> wT[n][k] bf16, gate/up INTERLEAVED ----
__global__ __launch_bounds__(256) void transpose_gu_kernel(
    const float* __restrict__ sgu, const float* __restrict__ egu,
    unsigned short* __restrict__ wT) {
  int e = blockIdx.z;
  const float* w = (e == 0) ? sgu : egu + (size_t)(e - 1) * D_DIM * TWO_I;
  unsigned short* o = wT + (size_t)e * NP2 * D_DIM;
  int k0 = blockIdx.x * 64, n0 = blockIdx.y * 32;
  __shared__ unsigned short lds[32][72];
  int tid = threadIdx.x;
  int nn = tid & 31, kr = tid >> 5;
  int n = n0 + nn;
  int hc = n >> 1;
  int src = (hc < I_DIM) ? ((n & 1) ? (I_DIM + hc) : hc) : -1;
  #pragma unroll
  for (int i = 0; i < 8; ++i) {
    int k = k0 + kr + i * 8;
    float f = (src >= 0) ? w[(size_t)k * TWO_I + src] : 0.f;
    lds[nn][kr + i * 8] = f2bf(f);
  }
  __syncthreads();
  int nr = tid >> 3, kc = (tid & 7) * 8;
  u16x8 v;
  #pragma unroll
  for (int j = 0; j < 8; ++j) v[j] = lds[nr][kc + j];
  *reinterpret_cast<u16x8*>(&o[(size_t)(n0 + nr) * D_DIM + k0 + kc]) = v;
}

// ---- transpose down: wd[k][n] -> wT[n][k] bf16, k padded to 1024 ----
__global__ __launch_bounds__(256) void transpose_d_kernel(
    const float* __restrict__ sdn, const float* __restrict__ edn,
    unsigned short* __restrict__ wT) {
  int e = blockIdx.z;
  const float* w = (e == 0) ? sdn : edn + (size_t)(e - 1) * I_DIM * D_DIM;
  unsigned short* o = wT + (size_t)e * D_DIM * IP;
  int k0 = blockIdx.x * 64, n0 = blockIdx.y * 32;
  __shared__ unsigned short lds[32][72];
  int tid = threadIdx.x;
  int nn = tid & 31, kr = tid >> 5;
  #pragma unroll
  for (int i = 0; i < 8; ++i) {
    int k = k0 + kr + i * 8;
    float f = (k < I_DIM) ? w[(size_t)k * D_DIM + n0 + nn] : 0.f;
    lds[nn][kr + i * 8] = f2bf(f);
  }
  __syncthreads();
  int nr = tid >> 3, kc = (tid & 7) * 8;
  u16x8 v;
  #pragma unroll
  for (int j = 0; j < 8; ++j) v[j] = lds[nr][kc + j];
  *reinterpret_cast<u16x8*>(&o[(size_t)(n0 + nr) * IP + k0 + kc]) = v;
}

// ------- GEMM1+SwiGLU: 256x256, BK=64, counted vmcnt + T2 swizzle + T5 -------
// LDS layout: slot (row, cs) holds global col (cs ^ ((row&7)<<3)) [shorts].
// gload_lds dest stays linear; SOURCE col pre-swizzled; reads apply same XOR.
__global__ __launch_bounds__(512) void gemm1_kernel(
    const unsigned short* __restrict__ xb,
    const unsigned short* __restrict__ wTgu,
    unsigned short* __restrict__ h_sh,
    unsigned short* __restrict__ h_g,
    const int* __restrict__ list, const int* __restrict__ cnt, int cap) {
  const int orig = blockIdx.x;
  const int wg = (orig & 7) * (gridDim.x >> 3) + (orig >> 3);   // bijective, 640%8==0
  int e, mb, nb;
  if (wg < 128) { e = 0; mb = wg >> 3; nb = wg & 7; }
  else { int r = wg - 128; e = 1 + (r >> 6); int rem = r & 63; mb = rem >> 3; nb = rem & 7; }
  const int m0 = mb * 256, n0 = nb * 256;
  int count = T_TOK;
  unsigned short* h = h_sh;
  if (e > 0) {
    count = min(cnt[e - 1], cap);
    if (m0 >= count) return;
    h = h_g + (size_t)(e - 1) * cap * IP;
  }
  const unsigned short* w = wTgu + (size_t)e * NP2 * D_DIM;

  __shared__ __align__(16) unsigned short a_lds[2][256 * 64];   // 64 KB
  __shared__ __align__(16) unsigned short b_lds[2][256 * 64];   // 64 KB
  const int tid = threadIdx.x;
  const int wave = tid >> 6, lane = tid & 63;
  const int mw = (wave >> 2) * 128, nw = (wave & 3) * 64;
  const int fr = lane & 15, fq = lane >> 4;
  const int srow = tid >> 3;
  const int sk = (tid & 7) * 8;                 // linear dest col (shorts)
  const int skSrc = sk ^ ((srow & 7) << 3);     // pre-swizzled source col
  const int cswz = (fr & 7) << 3;               // read-side XOR (row&7 == fr&7)

  size_t arow[4], brow[4];
  #pragma unroll
  for (int c = 0; c < 4; ++c) {
    int rr = m0 + 64 * c + srow;
    if (e > 0) rr = list[(e - 1) * cap + min(rr, count - 1)];
    arow[c] = (size_t)rr * D_DIM;
    brow[c] = (size_t)(n0 + 64 * c + srow) * D_DIM;
  }

  f32x4 acc[8][4];
  #pragma unroll
  for (int m = 0; m < 8; ++m)
    #pragma unroll
    for (int n = 0; n < 4; ++n) acc[m][n] = (f32x4)0.f;

  auto stage = [&](int buf, int k0) {   // 8 gload_lds per thread
    #pragma unroll
    for (int c = 0; c < 4; ++c) {
      gload16(xb + arow[c] + k0 + skSrc, &a_lds[buf][(64 * c + srow) * 64 + sk]);
      gload16(w + brow[c] + k0 + skSrc, &b_lds[buf][(64 * c + srow) * 64 + sk]);
    }
  };

  stage(0, 0);                        // 8 outstanding (buf0)
  int cur = 0;
  for (int t = 0; t < D_DIM / 64; ++t) {
    if (t + 1 < D_DIM / 64) {
      stage(cur ^ 1, (t + 1) * 64);   // +8 in flight (buf cur^1)
      asm volatile("s_waitcnt vmcnt(8)" ::: "memory");   // oldest 8 (cur) landed
    } else {
      asm volatile("s_waitcnt vmcnt(0)" ::: "memory");   // tail: drain cur
    }
    __builtin_amdgcn_s_barrier();     // all waves' cur-loads visible
    __builtin_amdgcn_s_setprio(1);
    #pragma unroll
    for (int kk = 0; kk < 2; ++kk) {
      bf16x8 av[8], bv[4];
      #pragma unroll
      for (int m = 0; m < 8; ++m)
        av[m] = *reinterpret_cast<const bf16x8*>(
            &a_lds[cur][(mw + m * 16 + fr) * 64 + ((kk * 32 + fq * 8) ^ cswz)]);
      #pragma unroll
      for (int n = 0; n < 4; ++n)
        bv[n] = *reinterpret_cast<const bf16x8*>(
            &b_lds[cur][(nw + n * 16 + fr) * 64 + ((kk * 32 + fq * 8) ^ cswz)]);
      #pragma unroll
      for (int m = 0; m < 8; ++m)
        #pragma unroll
        for (int n = 0; n < 4; ++n)
          acc[m][n] = __builtin_amdgcn_mfma_f32_16x16x32_bf16(av[m], bv[n], acc[m][n], 0, 0, 0);
    }
    __builtin_amdgcn_s_setprio(0);
    __builtin_amdgcn_s_barrier();     // done reading cur before it is restaged
    cur ^= 1;
  }
  // epilogue: even B-row = gate, odd = up (same h-col); pair via shfl_xor(1)
  const bool isGate = !(fr & 1);
  const int hcb = (n0 + nw) >> 1;
  #pragma unroll
  for (int m = 0; m < 8; ++m)
    #pragma unroll
    for (int n = 0; n < 4; ++n)
      #pragma unroll
      for (int q = 0; q < 4; ++q) {
        float v = acc[m][n][q];
        float pt = __shfl_xor(v, 1);
        if (isGate) {
          float hv = (v / (1.f + __expf(-v))) * pt;
          int trow = m0 + mw + m * 16 + fq * 4 + q;
          h[(size_t)trow * IP + hcb + n * 8 + (fr >> 1)] = f2bf(hv);
        }
      }
}

// ------- GEMM2: shared -> out (store); routed -> y_g (wgt folded); swizzled -------
__global__ __launch_bounds__(512) void gemm2_kernel(
    const unsigned short* __restrict__ h_sh,
    const unsigned short* __restrict__ h_g,
    const unsigned short* __restrict__ wTd,
    float* __restrict__ out, float* __restrict__ y_g,
    const float* __restrict__ wl, const int* __restrict__ cnt, int cap) {
  const int orig = blockIdx.x;
  const int wg = (orig & 7) * (gridDim.x >> 3) + (orig >> 3);   // 320%8==0
  int e, mb, nb;
  if (wg < 64) { e = -1; mb = wg >> 2; nb = wg & 3; }
  else { int r = wg - 64; e = r >> 5; int rem = r & 31; mb = rem >> 2; nb = rem & 3; }
  const int m0 = mb * 256, n0 = nb * 256;
  int count = T_TOK;
  const unsigned short* A = h_sh;
  if (e >= 0) {
    count = min(cnt[e], cap);
    if (m0 >= count) return;
    A = h_g + (size_t)e * cap * IP;
  }
  const unsigned short* B = wTd + (size_t)(e + 1) * D_DIM * IP;

  __shared__ __align__(16) unsigned short a_lds[2][256 * 64];
  __shared__ __align__(16) unsigned short b_lds[2][256 * 64];
  const int tid = threadIdx.x;
  const int wave = tid >> 6, lane = tid & 63;
  const int mw = (wave >> 2) * 128, nw = (wave & 3) * 64;
  const int fr = lane & 15, fq = lane >> 4;
  const int srow = tid >> 3;
  const int sk = (tid & 7) * 8;
  const int skSrc = sk ^ ((srow & 7) << 3);
  const int cswz = (fr & 7) << 3;

  f32x4 acc[8][4];
  #pragma unroll
  for (int m = 0; m < 8; ++m)
    #pragma unroll
    for (int n = 0; n < 4; ++n) acc[m][n] = (f32x4)0.f;

  auto stage = [&](int buf, int k0) {
    #pragma unroll
    for (int c = 0; c < 4; ++c) {
      gload16(A + (size_t)(m0 + 64 * c + srow) * IP + k0 + skSrc,
              &a_lds[buf][(64 * c + srow) * 64 + sk]);
      gload16(B + (size_t)(n0 + 64 * c + srow) * IP + k0 + skSrc,
              &b_lds[buf][(64 * c + srow) * 64 + sk]);
    }
  };
  stage(0, 0);
  int cur = 0;
  for (int t = 0; t < IP / 64; ++t) {
    if (t + 1 < IP / 64) {
      stage(cur ^ 1, (t + 1) * 64);
      asm volatile("s_waitcnt vmcnt(8)" ::: "memory");
    } else {
      asm volatile("s_waitcnt vmcnt(0)" ::: "memory");
    }
    __builtin_amdgcn_s_barrier();
    __builtin_amdgcn_s_setprio(1);
    #pragma unroll
    for (int kk = 0; kk < 2; ++kk) {
      bf16x8 av[8], bv[4];
      #pragma unroll
      for (int m = 0; m < 8; ++m)
        av[m] = *reinterpret_cast<const bf16x8*>(
            &a_lds[cur][(mw + m * 16 + fr) * 64 + ((kk * 32 + fq * 8) ^ cswz)]);
      #pragma unroll
      for (int n = 0; n < 4; ++n)
        bv[n] = *reinterpret_cast<const bf16x8*>(
            &b_lds[cur][(nw + n * 16 + fr) * 64 + ((kk * 32 + fq * 8) ^ cswz)]);
      #pragma unroll
      for (int m = 0; m < 8; ++m)
        #pragma unroll
        for (int n = 0; n < 4; ++n)
          acc[m][n] = __builtin_amdgcn_mfma_f32_16x16x32_bf16(av[m], bv[n], acc[m][n], 0, 0, 0);
    }
    __builtin_amdgcn_s_setprio(0);
    __builtin_amdgcn_s_barrier();
    cur ^= 1;
  }
  #pragma unroll
  for (int m = 0; m < 8; ++m)
    #pragma unroll
    for (int q = 0; q < 4; ++q) {
      int slot = m0 + mw + m * 16 + fq * 4 + q;
      if (slot < count) {
        if (e < 0) {
          #pragma unroll
          for (int n = 0; n < 4; ++n)
            out[(size_t)slot * D_DIM + n0 + nw + n * 16 + fr] = acc[m][n][q];
        } else {
          float wgt = wl[e * cap + slot];
          #pragma unroll
          for (int n = 0; n < 4; ++n)
            y_g[((size_t)e * cap + slot) * D_DIM + n0 + nw + n * 16 + fr] = wgt * acc[m][n][q];
        }
      }
    }
}

// ------- combine: out[t] += y_g[e1][s1] + y_g[e2][s2] -------
__global__ __launch_bounds__(256) void combine_kernel(
    float* __restrict__ out, const float* __restrict__ y_g,
    const int* __restrict__ ti, const int* __restrict__ sl,
    const int* __restrict__ cnt, int cap) {
  int t = blockIdx.x;
  int c = threadIdx.x * 4;
  float4 v = *reinterpret_cast<float4*>(&out[(size_t)t * D_DIM + c]);
  #pragma unroll
  for (int j = 0; j < 2; ++j) {
    int e = ti[2 * t + j], s = sl[2 * t + j];
    if (s < cap) {
      float4 y = *reinterpret_cast<const float4*>(&y_g[((size_t)e * cap + s) * D_DIM + c]);
      v.x += y.x; v.y += y.y; v.z += y.z; v.w += y.w;
    }
  }
  *reinterpret_cast<float4*>(&out[(size_t)t * D_DIM + c]) = v;
}

extern "C" void kernel_launch(void* const* d_in, const int* in_sizes, int n_in,
                              void* d_out, int out_size, void* d_ws, size_t ws_size,
                              hipStream_t stream) {
  const float* x   = (const float*)d_in[0];
  const float* gw  = (const float*)d_in[1];
  const float* sgu = (const float*)d_in[2];
  const float* sdn = (const float*)d_in[3];
  const float* egu = (const float*)d_in[4];
  const float* edn = (const float*)d_in[5];
  float* out = (float*)d_out;

  char* p = (char*)d_ws;
  unsigned short* xb   = (unsigned short*)p; p += (size_t)T_TOK * D_DIM * 2;
  unsigned short* wTgu = (unsigned short*)p; p += (size_t)9 * NP2 * D_DIM * 2;
  unsigned short* wTd  = (unsigned short*)p; p += (size_t)9 * D_DIM * IP * 2;
  unsigned short* h_sh = (unsigned short*)p; p += (size_t)T_TOK * IP * 2;

  size_t fixed_tail = (size_t)T_TOK * 2 * (4 + 4 + 4) + 64 + 256;
  size_t used = (size_t)(p - (char*)d_ws) + fixed_tail;
  size_t per_cap = (size_t)E_EXP * (IP * 2 + D_DIM * 4 + 4 + 4);  // h_g + y_g + list + wl
  long avail = (long)ws_size - (long)used;
  int cap = (int)(avail > 0 ? avail / (long)per_cap : 0);
  cap &= ~255;
  if (cap > 2048) cap = 2048;
  if (cap < 1536) cap = 1536;

  unsigned short* h_g = (unsigned short*)p; p += (size_t)E_EXP * cap * IP * 2;
  float* y_g  = (float*)p; p += (size_t)E_EXP * cap * D_DIM * 4;
  int*   ti   = (int*)p;   p += (size_t)T_TOK * 2 * 4;
  float* tw   = (float*)p; p += (size_t)T_TOK * 2 * 4;
  int*   sl   = (int*)p;   p += (size_t)T_TOK * 2 * 4;
  int*   list = (int*)p;   p += (size_t)E_EXP * cap * 4;
  float* wl   = (float*)p; p += (size_t)E_EXP * cap * 4;
  int*   cnt  = (int*)p;

  cvt_x_kernel<<<(T_TOK * D_DIM) / (4 * 256), 256, 0, stream>>>(x, xb);
  router_kernel<<<T_TOK / 4, 256, 0, stream>>>(x, gw, ti, tw);
  zero_cnt_kernel<<<1, 64, 0, stream>>>(cnt);
  assign_kernel<<<T_TOK / 256, 256, 0, stream>>>(ti, tw, cnt, list, wl, sl, cap);
  transpose_gu_kernel<<<dim3(D_DIM / 64, NP2 / 32, 9), 256, 0, stream>>>(sgu, egu, wTgu);
  transpose_d_kernel<<<dim3(IP / 64, D_DIM / 32, 9), 256, 0, stream>>>(sdn, edn, wTd);

  gemm1_kernel<<<128 + E_EXP * 64, 512, 0, stream>>>(xb, wTgu, h_sh, h_g, list, cnt, cap);
  gemm2_kernel<<<64 + E_EXP * 32, 512, 0, stream>>>(h_sh, h_g, wTd, out, y_g, wl, cnt, cap);
  combine_kernel<<<T_TOK, 256, 0, stream>>>(out, y_g, ti, sl, cnt, cap);
}